// Round 4
// baseline (4029.824 us; speedup 1.0000x reference)
//
#include <hip/hip_runtime.h>
#include <math.h>

#define TT 64
#define HZN 10
#define SBLK 128   // scan blocks
#define DBLK 256   // decoder blocks

__device__ __forceinline__ float sigm(float x) { return 1.f / (1.f + expf(-x)); }
__device__ __forceinline__ float gelu_f(float x) { return 0.5f * x * (1.f + erff(x * 0.70710678118654752f)); }

__device__ __forceinline__ float cLd(const float* p) {
  return __hip_atomic_load(p, __ATOMIC_RELAXED, __HIP_MEMORY_SCOPE_AGENT);
}
__device__ __forceinline__ void cSt(float* p, float v) {
  __hip_atomic_store(p, v, __ATOMIC_RELAXED, __HIP_MEMORY_SCOPE_AGENT);
}

// round-2 proven detector barrier: parallel flag stores + block-0 detector + gen release
template<int NB>
__device__ __forceinline__ void gbar(unsigned* flags, unsigned* gen, int bid, int tid, unsigned& bgen) {
  ++bgen;
  __syncthreads();  // drains vmcnt per wave -> prior cSt globally visible
  if (bid == 0) {
    if (tid > 0 && tid < NB) {
      while (__hip_atomic_load(&flags[tid], __ATOMIC_RELAXED, __HIP_MEMORY_SCOPE_AGENT) < bgen)
        __builtin_amdgcn_s_sleep(1);
    }
    __syncthreads();
    if (tid == 0)
      __hip_atomic_store(gen, bgen, __ATOMIC_RELAXED, __HIP_MEMORY_SCOPE_AGENT);
  } else {
    if (tid == 0) {
      asm volatile("s_waitcnt vmcnt(0)" ::: "memory");
      __hip_atomic_store(&flags[bid], bgen, __ATOMIC_RELAXED, __HIP_MEMORY_SCOPE_AGENT);
      while (__hip_atomic_load(gen, __ATOMIC_RELAXED, __HIP_MEMORY_SCOPE_AGENT) < bgen)
        __builtin_amdgcn_s_sleep(1);
    }
    __syncthreads();
  }
}

__device__ __forceinline__ void red32(float (&a)[4][4]) {
#pragma unroll
  for (int q = 0; q < 4; ++q)
#pragma unroll
    for (int r = 0; r < 4; ++r) {
      float v = a[q][r];
      v += __shfl_xor(v, 16); v += __shfl_xor(v, 8); v += __shfl_xor(v, 4);
      v += __shfl_xor(v, 2);  v += __shfl_xor(v, 1);
      a[q][r] = v;
    }
}

__device__ __forceinline__ void red64(float (&a)[4][4]) {
#pragma unroll
  for (int q = 0; q < 4; ++q)
#pragma unroll
    for (int r = 0; r < 4; ++r) {
      float v = a[q][r];
      v += __shfl_xor(v, 32); v += __shfl_xor(v, 16); v += __shfl_xor(v, 8);
      v += __shfl_xor(v, 4);  v += __shfl_xor(v, 2);  v += __shfl_xor(v, 1);
      a[q][r] = v;
    }
}

// ---------------------------------------------------------------- setup
__global__ void setup_kernel(const int* __restrict__ ei, const float* __restrict__ ew,
                             int* __restrict__ cptr, int* __restrict__ csrc, float* __restrict__ cnorm) {
  __shared__ float deg[100];
  __shared__ float dinv[100];
  __shared__ int cnt[100];
  __shared__ int pos[100];
  __shared__ int ptr[101];
  const int t = threadIdx.x;
  if (t < 100) { deg[t] = 0.f; cnt[t] = 0; }
  __syncthreads();
  for (int e = t; e < 2000; e += 256) {
    int c = ei[2000 + e];
    atomicAdd(&deg[c], ew[e]);
    atomicAdd(&cnt[c], 1);
  }
  __syncthreads();
  if (t < 100) dinv[t] = (deg[t] > 0.f) ? 1.f / sqrtf(fmaxf(deg[t], 1e-12f)) : 0.f;
  if (t == 0) {
    ptr[0] = 0;
    for (int n = 0; n < 100; ++n) ptr[n + 1] = ptr[n] + cnt[n];
  }
  __syncthreads();
  if (t < 100) pos[t] = ptr[t];
  if (t < 101) cptr[t] = ptr[t];
  __syncthreads();
  for (int e = t; e < 2000; e += 256) {
    int r = ei[e], c = ei[2000 + e];
    int p = atomicAdd(&pos[c], 1);
    csrc[p] = r;
    cnorm[p] = dinv[r] * ew[e] * dinv[c];
  }
}

// ---------------------------------------------------------------- fp32 -> bf16 (RNE)
__global__ void cvt_bf16(const float* __restrict__ src, unsigned short* __restrict__ dst, int n) {
  int i = blockIdx.x * 256 + threadIdx.x;
  if (i < n) {
    unsigned u = __float_as_uint(src[i]);
    unsigned r = (u + 0x7fffu + ((u >> 16) & 1u)) >> 16;
    dst[i] = (unsigned short)r;
  }
}

// ---------------------------------------------------------------- TGConv -> XS[T][B][3200]
__global__ void xs_kernel(const float* __restrict__ win,
                          const int* __restrict__ cptr, const int* __restrict__ csrc,
                          const float* __restrict__ cnorm,
                          const float* __restrict__ tgw, const float* __restrict__ tgv,
                          const float* __restrict__ tgb, const float* __restrict__ Wemb,
                          float* __restrict__ XS) {
  const int g = blockIdx.x * 256 + threadIdx.x;
  if (g >= 102400) return;
  const int n2 = g % 100;
  const int base = g - n2;
  float s = 0.f;
  const int p0 = cptr[n2], p1 = cptr[n2 + 1];
  for (int p = p0; p < p1; ++p) s += cnorm[p] * win[base + csrc[p]];
  const float x = win[g];
  const int t = g % 64;
  const int bb = g / 6400;
  const int n = (g / 64) % 100;
  float* dst = XS + (size_t)(t * 16 + bb) * 3200 + n * 32;
  for (int c = 0; c < 32; ++c) {
    float v = s * tgw[c] + x * tgv[c] + tgb[c];
    dst[c] = gelu_f(v) + Wemb[n * 32 + c];
  }
}

// ---------------------------------------------------------------- G0 = XS @ Wih0^T + biases
__global__ __launch_bounds__(256) void g0_gemm(const float* __restrict__ XS, const float* __restrict__ W,
                                               const float* __restrict__ b1, const float* __restrict__ b2,
                                               float* __restrict__ G0) {
  __shared__ float As[16][68];
  __shared__ float Bs[16][68];
  const int tid = threadIdx.x;
  const int m0 = blockIdx.y * 64, n0 = blockIdx.x * 64;
  const int tx = tid & 15, ty = tid >> 4;
  const int lr = tid >> 2, lk = (tid & 3) * 4;
  float acc[4][4] = {};
  for (int k0 = 0; k0 < 3200; k0 += 16) {
    float4 av = *(const float4*)&XS[(size_t)(m0 + lr) * 3200 + k0 + lk];
    float4 bv = *(const float4*)&W[(size_t)(n0 + lr) * 3200 + k0 + lk];
    As[lk + 0][lr] = av.x; As[lk + 1][lr] = av.y; As[lk + 2][lr] = av.z; As[lk + 3][lr] = av.w;
    Bs[lk + 0][lr] = bv.x; Bs[lk + 1][lr] = bv.y; Bs[lk + 2][lr] = bv.z; Bs[lk + 3][lr] = bv.w;
    __syncthreads();
#pragma unroll
    for (int kk = 0; kk < 16; ++kk) {
      float4 a = *(const float4*)&As[kk][ty * 4];
      float4 b = *(const float4*)&Bs[kk][tx * 4];
      acc[0][0] += a.x * b.x; acc[0][1] += a.x * b.y; acc[0][2] += a.x * b.z; acc[0][3] += a.x * b.w;
      acc[1][0] += a.y * b.x; acc[1][1] += a.y * b.y; acc[1][2] += a.y * b.z; acc[1][3] += a.y * b.w;
      acc[2][0] += a.z * b.x; acc[2][1] += a.z * b.y; acc[2][2] += a.z * b.z; acc[2][3] += a.z * b.w;
      acc[3][0] += a.w * b.x; acc[3][1] += a.w * b.y; acc[3][2] += a.w * b.z; acc[3][3] += a.w * b.w;
    }
    __syncthreads();
  }
#pragma unroll
  for (int i = 0; i < 4; ++i) {
    const int m = m0 + ty * 4 + i;
#pragma unroll
    for (int j = 0; j < 4; ++j) {
      const int nn = n0 + tx * 4 + j;
      G0[(size_t)m * 2048 + nn] = acc[i][j] + b1[nn] + b2[nn];
    }
  }
}

// ---------------------------------------------------------------- scan: 128 blocks x 1024 thr
struct ScanArgs {
  const float* G0;
  const float* Whh0;
  const float* Wih1; const float* Whh1; const float* bih1; const float* bhh1;
  float* hs0; float* hL1; float* c0; float* cL1;
  float* h1d; float* c1b; float* h2d; float* c2b;
  unsigned* flags; unsigned* gen;
};

__global__ __launch_bounds__(1024, 1) void scan_kernel(ScanArgs A) {
  __shared__ float lds[16384];
  const int tid = threadIdx.x;
  const int bid = blockIdx.x;
  const int gid = bid * 1024 + tid;
  unsigned bgen = 0;

  const int layer = bid >> 6;        // 0..1
  const int ublk = bid & 63;         // 64 per layer, 8 units each
  const int bg = tid >> 8;           // 4 batch groups
  const int du = (tid >> 5) & 7;     // 8 units per block
  const int s = tid & 31;            // K split
  const int n_s = ublk * 8 + du;

  for (int t2 = 0; t2 <= TT; ++t2) {
    if (layer == 0) {
      if (t2 < TT) {
        const int t0 = t2;
        float acc[4][4] = {};
        if (t0 > 0) {
          const float* src = A.hs0 + (size_t)(t0 - 1) * 8192;
#pragma unroll
          for (int i = 0; i < 8; ++i) lds[tid + i * 1024] = cLd(&src[tid + i * 1024]);
        }
        __syncthreads();
        if (t0 > 0) {
          for (int jj = 0; jj < 16; ++jj) {
            const int j = jj * 32 + s;
            const float w0 = A.Whh0[(n_s) * 512 + j];
            const float w1 = A.Whh0[(512 + n_s) * 512 + j];
            const float w2 = A.Whh0[(1024 + n_s) * 512 + j];
            const float w3 = A.Whh0[(1536 + n_s) * 512 + j];
#pragma unroll
            for (int br = 0; br < 4; ++br) {
              const float hv = lds[(bg * 4 + br) * 512 + j];
              acc[0][br] += w0 * hv; acc[1][br] += w1 * hv;
              acc[2][br] += w2 * hv; acc[3][br] += w3 * hv;
            }
          }
        }
        red32(acc);
        if (s == 0) {
#pragma unroll
          for (int br = 0; br < 4; ++br) {
            const int b = bg * 4 + br;
            const float* g0r = A.G0 + (size_t)(t0 * 16 + b) * 2048;
            const float gi = acc[0][br] + g0r[n_s];
            const float gf = acc[1][br] + g0r[512 + n_s];
            const float gg = acc[2][br] + g0r[1024 + n_s];
            const float go = acc[3][br] + g0r[1536 + n_s];
            const float cp = (t0 > 0) ? A.c0[b * 512 + n_s] : 0.f;
            const float cn = sigm(gf) * cp + sigm(gi) * tanhf(gg);
            const float hn = sigm(go) * tanhf(cn);
            A.c0[b * 512 + n_s] = cn;
            cSt(&A.hs0[(size_t)t0 * 8192 + b * 512 + n_s], hn);
          }
        }
      }
    } else {
      if (t2 >= 1) {
        const int t1 = t2 - 1;
        float acc[4][4] = {};
        {
          const float* sA = A.hs0 + (size_t)t1 * 8192;
#pragma unroll
          for (int i = 0; i < 8; ++i) lds[tid + i * 1024] = cLd(&sA[tid + i * 1024]);
          if (t1 > 0) {
            const float* sB = A.hL1 + (t1 & 1) * 8192;
#pragma unroll
            for (int i = 0; i < 8; ++i) lds[8192 + tid + i * 1024] = cLd(&sB[tid + i * 1024]);
          }
        }
        __syncthreads();
        for (int jj = 0; jj < 16; ++jj) {
          const int j = jj * 32 + s;
          const float wa0 = A.Wih1[(n_s) * 512 + j];
          const float wa1 = A.Wih1[(512 + n_s) * 512 + j];
          const float wa2 = A.Wih1[(1024 + n_s) * 512 + j];
          const float wa3 = A.Wih1[(1536 + n_s) * 512 + j];
#pragma unroll
          for (int br = 0; br < 4; ++br) {
            const float ha = lds[(bg * 4 + br) * 512 + j];
            acc[0][br] += wa0 * ha; acc[1][br] += wa1 * ha;
            acc[2][br] += wa2 * ha; acc[3][br] += wa3 * ha;
          }
          if (t1 > 0) {
            const float wb0 = A.Whh1[(n_s) * 512 + j];
            const float wb1 = A.Whh1[(512 + n_s) * 512 + j];
            const float wb2 = A.Whh1[(1024 + n_s) * 512 + j];
            const float wb3 = A.Whh1[(1536 + n_s) * 512 + j];
#pragma unroll
            for (int br = 0; br < 4; ++br) {
              const float hb = lds[8192 + (bg * 4 + br) * 512 + j];
              acc[0][br] += wb0 * hb; acc[1][br] += wb1 * hb;
              acc[2][br] += wb2 * hb; acc[3][br] += wb3 * hb;
            }
          }
        }
        red32(acc);
        if (s == 0) {
#pragma unroll
          for (int br = 0; br < 4; ++br) {
            const int b = bg * 4 + br;
            const float gi = acc[0][br] + A.bih1[n_s] + A.bhh1[n_s];
            const float gf = acc[1][br] + A.bih1[512 + n_s] + A.bhh1[512 + n_s];
            const float gg = acc[2][br] + A.bih1[1024 + n_s] + A.bhh1[1024 + n_s];
            const float go = acc[3][br] + A.bih1[1536 + n_s] + A.bhh1[1536 + n_s];
            const float cp = (t1 > 0) ? A.cL1[b * 512 + n_s] : 0.f;
            const float cn = sigm(gf) * cp + sigm(gi) * tanhf(gg);
            const float hn = sigm(go) * tanhf(cn);
            A.cL1[b * 512 + n_s] = cn;
            cSt(&A.hL1[((t1 & 1) ^ 1) * 8192 + b * 512 + n_s], hn);
          }
        }
      }
    }
    gbar<SBLK>(A.flags, A.gen, bid, tid, bgen);
  }

  // seed decoder state (dispatch boundary flushes caches for next kernel)
  if (gid < 8192) {
    const float h1v = cLd(&A.hs0[(size_t)63 * 8192 + gid]);
    A.h1d[gid] = h1v; A.c1b[gid] = h1v;
    const float h2v = cLd(&A.hL1[gid]);
    A.h2d[gid] = h2v; A.c2b[gid] = h2v;
  }
}

// ---------------------------------------------------------------- decoder (bf16 weights)
struct DecArgs {
  const unsigned short* c1Wih; const unsigned short* c1Whh;
  const float* c1bih; const float* c1bhh;
  const unsigned short* c2Wih; const unsigned short* c2Whh;
  const float* c2bih; const float* c2bhh;
  const float* Wp; const float* bp;
  const float* gw; const float* gv; const float* gb;
  const float* Wemb;
  const int* cptr; const int* csrc; const float* cnorm;
  float* h1d; float* c1b; float* h2d; float* c2b;
  unsigned* flags; unsigned* gen;
  float* out;
};

__device__ __forceinline__ void bf2(unsigned u, float& a, float& b) {
  a = __uint_as_float(u << 16);
  b = __uint_as_float(u & 0xffff0000u);
}

__global__ __launch_bounds__(512, 2) void dec_kernel(DecArgs A) {
  __shared__ float lds[15360];  // xin[12800] | h1l[2048] | predl[400]
  float* xinl = lds;
  float* h1l = lds + 12800;
  float* predl = lds + 14848;
  const int tid = threadIdx.x;
  const int bid = blockIdx.x;
  unsigned bgen = 0;

  const int uc = bid & 63, bq = bid >> 6;
  const int u = tid >> 6, sl = tid & 63;
  const int n = uc * 8 + u;

  for (int hz = 0; hz < HZN; ++hz) {
    const int cur = hz & 1, nxt = cur ^ 1;

    // ---- G1 phase: pred + graph conv + cell1 ----
    for (int i = tid; i < 2048; i += 512) {
      xinl[i] = cLd(&A.h2d[cur * 8192 + bq * 2048 + i]);
      h1l[i] = cLd(&A.h1d[cur * 8192 + bq * 2048 + i]);
    }
    __syncthreads();
    {
      const int d00 = tid >> 4, sp = tid & 15;
      for (int pass = 0; pass < 13; ++pass) {
        const int d = pass * 32 + d00;
        if (d < 400) {
          const int pb = d / 100, pn = d - pb * 100;
          const float* h2r = xinl + pb * 512;
          const float* wpr = A.Wp + pn * 512;
          float a = 0.f;
          for (int jj = 0; jj < 32; ++jj) { const int j = jj * 16 + sp; a += h2r[j] * wpr[j]; }
          a += __shfl_xor(a, 1); a += __shfl_xor(a, 2); a += __shfl_xor(a, 4); a += __shfl_xor(a, 8);
          if (sp == 0) predl[d] = a + A.bp[pn];
        }
      }
    }
    __syncthreads();
    if (uc == 0) {
      for (int i = tid; i < 400; i += 512) {
        const int bl = i / 100, n2 = i - bl * 100;
        A.out[((bq * 4 + bl) * 100 + n2) * HZN + hz] = predl[i];
      }
    }
    for (int k = 0; k < 25; ++k) {
      const int idx = k * 512 + tid;
      const int bl = idx / 3200, rem = idx - bl * 3200;
      const int n2 = rem >> 5, c = rem & 31;
      float s2 = 0.f;
      const int p0 = A.cptr[n2], p1 = A.cptr[n2 + 1];
      for (int p = p0; p < p1; ++p) s2 += A.cnorm[p] * predl[bl * 100 + A.csrc[p]];
      const float pv = predl[bl * 100 + n2];
      const float v = s2 * A.gw[c] + pv * A.gv[c] + A.gb[c];
      xinl[idx] = gelu_f(v) + A.Wemb[n2 * 32 + c];
    }
    __syncthreads();
    // cell1 gates: K = 3200 (xin, bf16 W) + 512 (h1, bf16 W)
    {
      float acc[4][4] = {};
      for (int jj = 0; jj < 25; ++jj) {
        const int j = jj * 128 + sl * 2;
        const unsigned u0 = *(const unsigned*)&A.c1Wih[(size_t)(n) * 3200 + j];
        const unsigned u1 = *(const unsigned*)&A.c1Wih[(size_t)(512 + n) * 3200 + j];
        const unsigned u2 = *(const unsigned*)&A.c1Wih[(size_t)(1024 + n) * 3200 + j];
        const unsigned u3 = *(const unsigned*)&A.c1Wih[(size_t)(1536 + n) * 3200 + j];
        float w0a, w0b, w1a, w1b, w2a, w2b, w3a, w3b;
        bf2(u0, w0a, w0b); bf2(u1, w1a, w1b); bf2(u2, w2a, w2b); bf2(u3, w3a, w3b);
#pragma unroll
        for (int bl = 0; bl < 4; ++bl) {
          const float2 xv = *(const float2*)&xinl[bl * 3200 + j];
          acc[0][bl] += w0a * xv.x + w0b * xv.y;
          acc[1][bl] += w1a * xv.x + w1b * xv.y;
          acc[2][bl] += w2a * xv.x + w2b * xv.y;
          acc[3][bl] += w3a * xv.x + w3b * xv.y;
        }
      }
      for (int jj = 0; jj < 4; ++jj) {
        const int j = jj * 128 + sl * 2;
        const unsigned u0 = *(const unsigned*)&A.c1Whh[(n) * 512 + j];
        const unsigned u1 = *(const unsigned*)&A.c1Whh[(512 + n) * 512 + j];
        const unsigned u2 = *(const unsigned*)&A.c1Whh[(1024 + n) * 512 + j];
        const unsigned u3 = *(const unsigned*)&A.c1Whh[(1536 + n) * 512 + j];
        float w0a, w0b, w1a, w1b, w2a, w2b, w3a, w3b;
        bf2(u0, w0a, w0b); bf2(u1, w1a, w1b); bf2(u2, w2a, w2b); bf2(u3, w3a, w3b);
#pragma unroll
        for (int bl = 0; bl < 4; ++bl) {
          const float2 hv = *(const float2*)&h1l[bl * 512 + j];
          acc[0][bl] += w0a * hv.x + w0b * hv.y;
          acc[1][bl] += w1a * hv.x + w1b * hv.y;
          acc[2][bl] += w2a * hv.x + w2b * hv.y;
          acc[3][bl] += w3a * hv.x + w3b * hv.y;
        }
      }
      red64(acc);
      if (sl == 0) {
#pragma unroll
        for (int bl = 0; bl < 4; ++bl) {
          const int b = bq * 4 + bl;
          const float gi = acc[0][bl] + A.c1bih[n] + A.c1bhh[n];
          const float gf = acc[1][bl] + A.c1bih[512 + n] + A.c1bhh[512 + n];
          const float gg = acc[2][bl] + A.c1bih[1024 + n] + A.c1bhh[1024 + n];
          const float go = acc[3][bl] + A.c1bih[1536 + n] + A.c1bhh[1536 + n];
          const float cp = A.c1b[b * 512 + n];
          const float cn = sigm(gf) * cp + sigm(gi) * tanhf(gg);
          const float hn = sigm(go) * tanhf(cn);
          A.c1b[b * 512 + n] = cn;
          cSt(&A.h1d[nxt * 8192 + b * 512 + n], hn);
        }
      }
    }
    gbar<DBLK>(A.flags, A.gen, bid, tid, bgen);

    // ---- G2 phase ----
    {
      float* hAl = lds;
      float* hBl = lds + 2048;
      for (int i = tid; i < 2048; i += 512) {
        hAl[i] = cLd(&A.h1d[nxt * 8192 + bq * 2048 + i]);
        hBl[i] = cLd(&A.h2d[cur * 8192 + bq * 2048 + i]);
      }
      __syncthreads();
      float acc[4][4] = {};
      for (int jj = 0; jj < 4; ++jj) {
        const int j = jj * 128 + sl * 2;
        const unsigned a0 = *(const unsigned*)&A.c2Wih[(n) * 512 + j];
        const unsigned a1 = *(const unsigned*)&A.c2Wih[(512 + n) * 512 + j];
        const unsigned a2 = *(const unsigned*)&A.c2Wih[(1024 + n) * 512 + j];
        const unsigned a3 = *(const unsigned*)&A.c2Wih[(1536 + n) * 512 + j];
        const unsigned b0 = *(const unsigned*)&A.c2Whh[(n) * 512 + j];
        const unsigned b1 = *(const unsigned*)&A.c2Whh[(512 + n) * 512 + j];
        const unsigned b2 = *(const unsigned*)&A.c2Whh[(1024 + n) * 512 + j];
        const unsigned b3 = *(const unsigned*)&A.c2Whh[(1536 + n) * 512 + j];
        float wa0a, wa0b, wa1a, wa1b, wa2a, wa2b, wa3a, wa3b;
        float wb0a, wb0b, wb1a, wb1b, wb2a, wb2b, wb3a, wb3b;
        bf2(a0, wa0a, wa0b); bf2(a1, wa1a, wa1b); bf2(a2, wa2a, wa2b); bf2(a3, wa3a, wa3b);
        bf2(b0, wb0a, wb0b); bf2(b1, wb1a, wb1b); bf2(b2, wb2a, wb2b); bf2(b3, wb3a, wb3b);
#pragma unroll
        for (int bl = 0; bl < 4; ++bl) {
          const float2 ha = *(const float2*)&hAl[bl * 512 + j];
          const float2 hb = *(const float2*)&hBl[bl * 512 + j];
          acc[0][bl] += wa0a * ha.x + wa0b * ha.y + wb0a * hb.x + wb0b * hb.y;
          acc[1][bl] += wa1a * ha.x + wa1b * ha.y + wb1a * hb.x + wb1b * hb.y;
          acc[2][bl] += wa2a * ha.x + wa2b * ha.y + wb2a * hb.x + wb2b * hb.y;
          acc[3][bl] += wa3a * ha.x + wa3b * ha.y + wb3a * hb.x + wb3b * hb.y;
        }
      }
      red64(acc);
      if (sl == 0) {
#pragma unroll
        for (int bl = 0; bl < 4; ++bl) {
          const int b = bq * 4 + bl;
          const float gi = acc[0][bl] + A.c2bih[n] + A.c2bhh[n];
          const float gf = acc[1][bl] + A.c2bih[512 + n] + A.c2bhh[512 + n];
          const float gg = acc[2][bl] + A.c2bih[1024 + n] + A.c2bhh[1024 + n];
          const float go = acc[3][bl] + A.c2bih[1536 + n] + A.c2bhh[1536 + n];
          const float cp = A.c2b[b * 512 + n];
          const float cn = sigm(gf) * cp + sigm(gi) * tanhf(gg);
          const float hn = sigm(go) * tanhf(cn);
          A.c2b[b * 512 + n] = cn;
          cSt(&A.h2d[nxt * 8192 + b * 512 + n], hn);
        }
      }
    }
    gbar<DBLK>(A.flags, A.gen, bid, tid, bgen);
  }
}

// ---------------------------------------------------------------- launch
extern "C" void kernel_launch(void* const* d_in, const int* in_sizes, int n_in,
                              void* d_out, int out_size, void* d_ws, size_t ws_size,
                              hipStream_t stream) {
  (void)in_sizes; (void)n_in; (void)out_size; (void)ws_size;
  const float* window = (const float*)d_in[0];
  const int* ei = (const int*)d_in[1];
  const float* ew = (const float*)d_in[2];
  const float* Wemb = (const float*)d_in[3];
  const float* tgw = (const float*)d_in[4];
  const float* tgv = (const float*)d_in[5];
  const float* tgb = (const float*)d_in[6];
  const float* gw = (const float*)d_in[7];
  const float* gv = (const float*)d_in[8];
  const float* gb = (const float*)d_in[9];
  const float* Wih0 = (const float*)d_in[10];
  const float* Whh0 = (const float*)d_in[11];
  const float* bih0 = (const float*)d_in[12];
  const float* bhh0 = (const float*)d_in[13];
  const float* Wih1 = (const float*)d_in[14];
  const float* Whh1 = (const float*)d_in[15];
  const float* bih1 = (const float*)d_in[16];
  const float* bhh1 = (const float*)d_in[17];
  const float* c1Wih = (const float*)d_in[18];
  const float* c1Whh = (const float*)d_in[19];
  const float* c1bih = (const float*)d_in[20];
  const float* c1bhh = (const float*)d_in[21];
  const float* c2Wih = (const float*)d_in[22];
  const float* c2Whh = (const float*)d_in[23];
  const float* c2bih = (const float*)d_in[24];
  const float* c2bhh = (const float*)d_in[25];
  const float* Wp = (const float*)d_in[26];
  const float* bp = (const float*)d_in[27];

  char* w = (char*)d_ws;
  size_t off = 0;
  auto alloc = [&](size_t bytes) { void* p = w + off; off = (off + bytes + 255) & ~(size_t)255; return p; };
  int* cptr = (int*)alloc(101 * 4);
  int* csrc = (int*)alloc(2000 * 4);
  float* cnorm = (float*)alloc(2000 * 4);
  float* XS = (float*)alloc((size_t)1024 * 3200 * 4);
  float* G0 = (float*)alloc((size_t)1024 * 2048 * 4);
  float* hs0 = (float*)alloc((size_t)64 * 8192 * 4);
  float* hL1 = (float*)alloc((size_t)2 * 8192 * 4);
  float* c0 = (float*)alloc((size_t)8192 * 4);
  float* cL1 = (float*)alloc((size_t)8192 * 4);
  float* h1d = (float*)alloc((size_t)2 * 8192 * 4);
  float* c1b = (float*)alloc((size_t)8192 * 4);
  float* h2d = (float*)alloc((size_t)2 * 8192 * 4);
  float* c2b = (float*)alloc((size_t)8192 * 4);
  unsigned short* c1Wih_bf = (unsigned short*)alloc((size_t)2048 * 3200 * 2);
  unsigned short* c1Whh_bf = (unsigned short*)alloc((size_t)2048 * 512 * 2);
  unsigned short* c2Wih_bf = (unsigned short*)alloc((size_t)2048 * 512 * 2);
  unsigned short* c2Whh_bf = (unsigned short*)alloc((size_t)2048 * 512 * 2);
  unsigned* flags1 = (unsigned*)alloc(SBLK * 4);
  unsigned* gen1 = (unsigned*)alloc(64);
  unsigned* flags2 = (unsigned*)alloc(DBLK * 4);
  unsigned* gen2 = (unsigned*)alloc(64);

  hipMemsetAsync(flags1, 0, SBLK * 4, stream);
  hipMemsetAsync(gen1, 0, 4, stream);
  hipMemsetAsync(flags2, 0, DBLK * 4, stream);
  hipMemsetAsync(gen2, 0, 4, stream);

  setup_kernel<<<1, 256, 0, stream>>>(ei, ew, cptr, csrc, cnorm);
  cvt_bf16<<<(2048 * 3200 + 255) / 256, 256, 0, stream>>>(c1Wih, c1Wih_bf, 2048 * 3200);
  cvt_bf16<<<(2048 * 512 + 255) / 256, 256, 0, stream>>>(c1Whh, c1Whh_bf, 2048 * 512);
  cvt_bf16<<<(2048 * 512 + 255) / 256, 256, 0, stream>>>(c2Wih, c2Wih_bf, 2048 * 512);
  cvt_bf16<<<(2048 * 512 + 255) / 256, 256, 0, stream>>>(c2Whh, c2Whh_bf, 2048 * 512);
  xs_kernel<<<400, 256, 0, stream>>>(window, cptr, csrc, cnorm, tgw, tgv, tgb, Wemb, XS);
  g0_gemm<<<dim3(32, 16), 256, 0, stream>>>(XS, Wih0, bih0, bhh0, G0);

  ScanArgs S;
  S.G0 = G0; S.Whh0 = Whh0;
  S.Wih1 = Wih1; S.Whh1 = Whh1; S.bih1 = bih1; S.bhh1 = bhh1;
  S.hs0 = hs0; S.hL1 = hL1; S.c0 = c0; S.cL1 = cL1;
  S.h1d = h1d; S.c1b = c1b; S.h2d = h2d; S.c2b = c2b;
  S.flags = flags1; S.gen = gen1;
  void* sp[] = { &S };
  hipLaunchCooperativeKernel(scan_kernel, dim3(SBLK), dim3(1024), sp, 0, stream);

  DecArgs D;
  D.c1Wih = c1Wih_bf; D.c1Whh = c1Whh_bf; D.c1bih = c1bih; D.c1bhh = c1bhh;
  D.c2Wih = c2Wih_bf; D.c2Whh = c2Whh_bf; D.c2bih = c2bih; D.c2bhh = c2bhh;
  D.Wp = Wp; D.bp = bp; D.gw = gw; D.gv = gv; D.gb = gb; D.Wemb = Wemb;
  D.cptr = cptr; D.csrc = csrc; D.cnorm = cnorm;
  D.h1d = h1d; D.c1b = c1b; D.h2d = h2d; D.c2b = c2b;
  D.flags = flags2; D.gen = gen2;
  D.out = (float*)d_out;
  void* dp[] = { &D };
  hipLaunchCooperativeKernel(dec_kernel, dim3(DBLK), dim3(512), dp, 0, stream);
}

// Round 5
// 2352.173 us; speedup vs baseline: 1.7132x; 1.7132x over previous
//
#include <hip/hip_runtime.h>
#include <math.h>

#define TT 64
#define HZN 10
#define NBLK 256

__device__ __forceinline__ float sigm(float x) { return 1.f / (1.f + expf(-x)); }
__device__ __forceinline__ float gelu_f(float x) { return 0.5f * x * (1.f + erff(x * 0.70710678118654752f)); }

// agent-scope coherent accessors (bypass non-coherent per-XCD L2)
__device__ __forceinline__ float cLd(const float* p) {
  return __hip_atomic_load(p, __ATOMIC_RELAXED, __HIP_MEMORY_SCOPE_AGENT);
}
__device__ __forceinline__ void cSt(float* p, float v) {
  __hip_atomic_store(p, v, __ATOMIC_RELAXED, __HIP_MEMORY_SCOPE_AGENT);
}
// coherent 16B load; caller MUST s_waitcnt vmcnt(0) before using the result
__device__ __forceinline__ float4 cLd4(const float4* p) {
  float4 d;
  asm volatile("global_load_dwordx4 %0, %1, off sc0 sc1" : "=v"(d) : "v"(p));
  return d;
}
__device__ __forceinline__ void vwait() {
  asm volatile("s_waitcnt vmcnt(0)" ::: "memory");
  __builtin_amdgcn_sched_barrier(0);
}

// round-2 proven detector barrier
__device__ __forceinline__ void gbar(unsigned* flags, unsigned* gen, int bid, int tid, unsigned& bgen) {
  ++bgen;
  __syncthreads();  // drains vmcnt per wave -> prior cSt globally visible
  if (bid == 0) {
    if (tid > 0 && tid < NBLK) {
      while (__hip_atomic_load(&flags[tid], __ATOMIC_RELAXED, __HIP_MEMORY_SCOPE_AGENT) < bgen)
        __builtin_amdgcn_s_sleep(1);
    }
    __syncthreads();
    if (tid == 0)
      __hip_atomic_store(gen, bgen, __ATOMIC_RELAXED, __HIP_MEMORY_SCOPE_AGENT);
  } else {
    if (tid == 0) {
      asm volatile("s_waitcnt vmcnt(0)" ::: "memory");
      __hip_atomic_store(&flags[bid], bgen, __ATOMIC_RELAXED, __HIP_MEMORY_SCOPE_AGENT);
      while (__hip_atomic_load(gen, __ATOMIC_RELAXED, __HIP_MEMORY_SCOPE_AGENT) < bgen)
        __builtin_amdgcn_s_sleep(1);
    }
    __syncthreads();
  }
}

__device__ __forceinline__ void red32(float (&a)[4][4]) {
#pragma unroll
  for (int q = 0; q < 4; ++q)
#pragma unroll
    for (int r = 0; r < 4; ++r) {
      float v = a[q][r];
      v += __shfl_xor(v, 16); v += __shfl_xor(v, 8); v += __shfl_xor(v, 4);
      v += __shfl_xor(v, 2);  v += __shfl_xor(v, 1);
      a[q][r] = v;
    }
}

__device__ __forceinline__ void red64(float (&a)[4][4]) {
#pragma unroll
  for (int q = 0; q < 4; ++q)
#pragma unroll
    for (int r = 0; r < 4; ++r) {
      float v = a[q][r];
      v += __shfl_xor(v, 32); v += __shfl_xor(v, 16); v += __shfl_xor(v, 8);
      v += __shfl_xor(v, 4);  v += __shfl_xor(v, 2);  v += __shfl_xor(v, 1);
      a[q][r] = v;
    }
}

// ---------------------------------------------------------------- setup
__global__ void setup_kernel(const int* __restrict__ ei, const float* __restrict__ ew,
                             int* __restrict__ cptr, int* __restrict__ csrc, float* __restrict__ cnorm) {
  __shared__ float deg[100];
  __shared__ float dinv[100];
  __shared__ int cnt[100];
  __shared__ int pos[100];
  __shared__ int ptr[101];
  const int t = threadIdx.x;
  if (t < 100) { deg[t] = 0.f; cnt[t] = 0; }
  __syncthreads();
  for (int e = t; e < 2000; e += 256) {
    int c = ei[2000 + e];
    atomicAdd(&deg[c], ew[e]);
    atomicAdd(&cnt[c], 1);
  }
  __syncthreads();
  if (t < 100) dinv[t] = (deg[t] > 0.f) ? 1.f / sqrtf(fmaxf(deg[t], 1e-12f)) : 0.f;
  if (t == 0) {
    ptr[0] = 0;
    for (int n = 0; n < 100; ++n) ptr[n + 1] = ptr[n] + cnt[n];
  }
  __syncthreads();
  if (t < 100) pos[t] = ptr[t];
  if (t < 101) cptr[t] = ptr[t];
  __syncthreads();
  for (int e = t; e < 2000; e += 256) {
    int r = ei[e], c = ei[2000 + e];
    int p = atomicAdd(&pos[c], 1);
    csrc[p] = r;
    cnorm[p] = dinv[r] * ew[e] * dinv[c];
  }
}

// ---------------------------------------------------------------- fp32 -> bf16 (RNE)
__global__ void cvt_bf16(const float* __restrict__ src, unsigned short* __restrict__ dst, int n) {
  int i = blockIdx.x * 256 + threadIdx.x;
  if (i < n) {
    unsigned u = __float_as_uint(src[i]);
    unsigned r = (u + 0x7fffu + ((u >> 16) & 1u)) >> 16;
    dst[i] = (unsigned short)r;
  }
}

// ---------------------------------------------------------------- TGConv -> XS[T][B][3200]
__global__ void xs_kernel(const float* __restrict__ win,
                          const int* __restrict__ cptr, const int* __restrict__ csrc,
                          const float* __restrict__ cnorm,
                          const float* __restrict__ tgw, const float* __restrict__ tgv,
                          const float* __restrict__ tgb, const float* __restrict__ Wemb,
                          float* __restrict__ XS) {
  const int g = blockIdx.x * 256 + threadIdx.x;
  if (g >= 102400) return;
  const int n2 = g % 100;
  const int base = g - n2;
  float s = 0.f;
  const int p0 = cptr[n2], p1 = cptr[n2 + 1];
  for (int p = p0; p < p1; ++p) s += cnorm[p] * win[base + csrc[p]];
  const float x = win[g];
  const int t = g % 64;
  const int bb = g / 6400;
  const int n = (g / 64) % 100;
  float* dst = XS + (size_t)(t * 16 + bb) * 3200 + n * 32;
  for (int c = 0; c < 32; ++c) {
    float v = s * tgw[c] + x * tgv[c] + tgb[c];
    dst[c] = gelu_f(v) + Wemb[n * 32 + c];
  }
}

// ---------------------------------------------------------------- G0 = XS @ Wih0^T + biases
__global__ __launch_bounds__(256) void g0_gemm(const float* __restrict__ XS, const float* __restrict__ W,
                                               const float* __restrict__ b1, const float* __restrict__ b2,
                                               float* __restrict__ G0) {
  __shared__ float As[16][68];
  __shared__ float Bs[16][68];
  const int tid = threadIdx.x;
  const int m0 = blockIdx.y * 64, n0 = blockIdx.x * 64;
  const int tx = tid & 15, ty = tid >> 4;
  const int lr = tid >> 2, lk = (tid & 3) * 4;
  float acc[4][4] = {};
  for (int k0 = 0; k0 < 3200; k0 += 16) {
    float4 av = *(const float4*)&XS[(size_t)(m0 + lr) * 3200 + k0 + lk];
    float4 bv = *(const float4*)&W[(size_t)(n0 + lr) * 3200 + k0 + lk];
    As[lk + 0][lr] = av.x; As[lk + 1][lr] = av.y; As[lk + 2][lr] = av.z; As[lk + 3][lr] = av.w;
    Bs[lk + 0][lr] = bv.x; Bs[lk + 1][lr] = bv.y; Bs[lk + 2][lr] = bv.z; Bs[lk + 3][lr] = bv.w;
    __syncthreads();
#pragma unroll
    for (int kk = 0; kk < 16; ++kk) {
      float4 a = *(const float4*)&As[kk][ty * 4];
      float4 b = *(const float4*)&Bs[kk][tx * 4];
      acc[0][0] += a.x * b.x; acc[0][1] += a.x * b.y; acc[0][2] += a.x * b.z; acc[0][3] += a.x * b.w;
      acc[1][0] += a.y * b.x; acc[1][1] += a.y * b.y; acc[1][2] += a.y * b.z; acc[1][3] += a.y * b.w;
      acc[2][0] += a.z * b.x; acc[2][1] += a.z * b.y; acc[2][2] += a.z * b.z; acc[2][3] += a.z * b.w;
      acc[3][0] += a.w * b.x; acc[3][1] += a.w * b.y; acc[3][2] += a.w * b.z; acc[3][3] += a.w * b.w;
    }
    __syncthreads();
  }
#pragma unroll
  for (int i = 0; i < 4; ++i) {
    const int m = m0 + ty * 4 + i;
#pragma unroll
    for (int j = 0; j < 4; ++j) {
      const int nn = n0 + tx * 4 + j;
      G0[(size_t)m * 2048 + nn] = acc[i][j] + b1[nn] + b2[nn];
    }
  }
}

// ---------------------------------------------------------------- cooperative: scan + decoder
struct CoopArgs {
  const float* G0;
  const float* Whh0;
  const float* Wih1; const float* Whh1; const float* bih1; const float* bhh1;
  const unsigned short* c1Wih; const unsigned short* c1Whh;
  const float* c1bih; const float* c1bhh;
  const unsigned short* c2Wih; const unsigned short* c2Whh;
  const float* c2bih; const float* c2bhh;
  const float* Wp; const float* bp;
  const float* gw; const float* gv; const float* gb;
  const float* Wemb;
  const int* cptr; const int* csrc; const float* cnorm;
  float* hs0; float* hL1; float* c0; float* cL1;
  float* h1d; float* c1b; float* h2d; float* c2b;
  unsigned* flags; unsigned* gen;
  float* out;
};

__device__ __forceinline__ void bf2(unsigned u, float& a, float& b) {
  a = __uint_as_float(u << 16);
  b = __uint_as_float(u & 0xffff0000u);
}

__global__ __launch_bounds__(512, 2) void coop_kernel(CoopArgs A) {
  __shared__ float lds[16384];  // 64 KB
  const int tid = threadIdx.x;
  const int bid = blockIdx.x;
  const int gid = bid * 512 + tid;
  unsigned bgen = 0;

  // ---- phase 1: pipelined LSTM0 + LSTM1 scan (65 iterations), round-2 layout ----
  const int layer = bid >> 7;
  const int ublk = bid & 127;
  const int u0 = ublk * 4;
  const int bg = tid >> 7;
  const int du = (tid >> 5) & 3;
  const int s = tid & 31;
  const int n_s = u0 + du;

  for (int t2 = 0; t2 <= TT; ++t2) {
    if (layer == 0) {
      if (t2 < TT) {
        const int t0 = t2;
        float acc[4][4] = {};
        if (t0 > 0) {
          const float4* src4 = (const float4*)(A.hs0 + (size_t)(t0 - 1) * 8192);
          float4 a0 = cLd4(src4 + tid);
          float4 a1 = cLd4(src4 + tid + 512);
          float4 a2 = cLd4(src4 + tid + 1024);
          float4 a3 = cLd4(src4 + tid + 1536);
          vwait();
          float4* d4 = (float4*)lds;
          d4[tid] = a0; d4[tid + 512] = a1; d4[tid + 1024] = a2; d4[tid + 1536] = a3;
        }
        __syncthreads();
        if (t0 > 0) {
          for (int jj = 0; jj < 16; ++jj) {
            const int j = jj * 32 + s;
            const float w0 = A.Whh0[(n_s) * 512 + j];
            const float w1 = A.Whh0[(512 + n_s) * 512 + j];
            const float w2 = A.Whh0[(1024 + n_s) * 512 + j];
            const float w3 = A.Whh0[(1536 + n_s) * 512 + j];
#pragma unroll
            for (int br = 0; br < 4; ++br) {
              const float hv = lds[(bg * 4 + br) * 512 + j];
              acc[0][br] += w0 * hv; acc[1][br] += w1 * hv;
              acc[2][br] += w2 * hv; acc[3][br] += w3 * hv;
            }
          }
        }
        red32(acc);
        if (s == 0) {
#pragma unroll
          for (int br = 0; br < 4; ++br) {
            const int b = bg * 4 + br;
            const float* g0r = A.G0 + (size_t)(t0 * 16 + b) * 2048;
            const float gi = acc[0][br] + g0r[n_s];
            const float gf = acc[1][br] + g0r[512 + n_s];
            const float gg = acc[2][br] + g0r[1024 + n_s];
            const float go = acc[3][br] + g0r[1536 + n_s];
            const float cp = (t0 > 0) ? A.c0[b * 512 + n_s] : 0.f;
            const float cn = sigm(gf) * cp + sigm(gi) * tanhf(gg);
            const float hn = sigm(go) * tanhf(cn);
            A.c0[b * 512 + n_s] = cn;
            cSt(&A.hs0[(size_t)t0 * 8192 + b * 512 + n_s], hn);
          }
        }
      }
    } else {
      if (t2 >= 1) {
        const int t1 = t2 - 1;
        float acc[4][4] = {};
        {
          const float4* sA = (const float4*)(A.hs0 + (size_t)t1 * 8192);
          float4 a0 = cLd4(sA + tid);
          float4 a1 = cLd4(sA + tid + 512);
          float4 a2 = cLd4(sA + tid + 1024);
          float4 a3 = cLd4(sA + tid + 1536);
          float4 b0, b1, b2, b3;
          if (t1 > 0) {
            const float4* sB = (const float4*)(A.hL1 + (t1 & 1) * 8192);
            b0 = cLd4(sB + tid);
            b1 = cLd4(sB + tid + 512);
            b2 = cLd4(sB + tid + 1024);
            b3 = cLd4(sB + tid + 1536);
          }
          vwait();
          float4* dA = (float4*)lds;
          dA[tid] = a0; dA[tid + 512] = a1; dA[tid + 1024] = a2; dA[tid + 1536] = a3;
          if (t1 > 0) {
            float4* dB = (float4*)(lds + 8192);
            dB[tid] = b0; dB[tid + 512] = b1; dB[tid + 1024] = b2; dB[tid + 1536] = b3;
          }
        }
        __syncthreads();
        for (int jj = 0; jj < 16; ++jj) {
          const int j = jj * 32 + s;
          const float wa0 = A.Wih1[(n_s) * 512 + j];
          const float wa1 = A.Wih1[(512 + n_s) * 512 + j];
          const float wa2 = A.Wih1[(1024 + n_s) * 512 + j];
          const float wa3 = A.Wih1[(1536 + n_s) * 512 + j];
#pragma unroll
          for (int br = 0; br < 4; ++br) {
            const float ha = lds[(bg * 4 + br) * 512 + j];
            acc[0][br] += wa0 * ha; acc[1][br] += wa1 * ha;
            acc[2][br] += wa2 * ha; acc[3][br] += wa3 * ha;
          }
          if (t1 > 0) {
            const float wb0 = A.Whh1[(n_s) * 512 + j];
            const float wb1 = A.Whh1[(512 + n_s) * 512 + j];
            const float wb2 = A.Whh1[(1024 + n_s) * 512 + j];
            const float wb3 = A.Whh1[(1536 + n_s) * 512 + j];
#pragma unroll
            for (int br = 0; br < 4; ++br) {
              const float hb = lds[8192 + (bg * 4 + br) * 512 + j];
              acc[0][br] += wb0 * hb; acc[1][br] += wb1 * hb;
              acc[2][br] += wb2 * hb; acc[3][br] += wb3 * hb;
            }
          }
        }
        red32(acc);
        if (s == 0) {
#pragma unroll
          for (int br = 0; br < 4; ++br) {
            const int b = bg * 4 + br;
            const float gi = acc[0][br] + A.bih1[n_s] + A.bhh1[n_s];
            const float gf = acc[1][br] + A.bih1[512 + n_s] + A.bhh1[512 + n_s];
            const float gg = acc[2][br] + A.bih1[1024 + n_s] + A.bhh1[1024 + n_s];
            const float go = acc[3][br] + A.bih1[1536 + n_s] + A.bhh1[1536 + n_s];
            const float cp = (t1 > 0) ? A.cL1[b * 512 + n_s] : 0.f;
            const float cn = sigm(gf) * cp + sigm(gi) * tanhf(gg);
            const float hn = sigm(go) * tanhf(cn);
            A.cL1[b * 512 + n_s] = cn;
            cSt(&A.hL1[((t1 & 1) ^ 1) * 8192 + b * 512 + n_s], hn);
          }
        }
      }
    }
    gbar(A.flags, A.gen, bid, tid, bgen);
  }

  // ---- seed decoder state ----
  if (gid < 8192) {
    const float h1v = cLd(&A.hs0[(size_t)63 * 8192 + gid]);
    cSt(&A.h1d[gid], h1v); cSt(&A.c1b[gid], h1v);
    const float h2v = cLd(&A.hL1[gid]);
    cSt(&A.h2d[gid], h2v); cSt(&A.c2b[gid], h2v);
  }
  gbar(A.flags, A.gen, bid, tid, bgen);

  // ---- decoder: 10 horizon steps, 2 phases each ----
  float* xinl = lds;           // 12800
  float* h1l = lds + 12800;    // 2048
  float* predl = lds + 14848;  // 400
  const int uc = bid & 63, bq = bid >> 6;
  const int u = tid >> 6, sl = tid & 63;
  const int n = uc * 8 + u;

  for (int hz = 0; hz < HZN; ++hz) {
    const int cur = hz & 1, nxt = cur ^ 1;

    // ---- G1 phase: pred + graph conv + cell1, all in-block ----
    {
      float4 h2v = cLd4((const float4*)(A.h2d + cur * 8192 + bq * 2048) + tid);
      float4 h1v = cLd4((const float4*)(A.h1d + cur * 8192 + bq * 2048) + tid);
      vwait();
      ((float4*)xinl)[tid] = h2v;  // h2 staged temporarily at xinl[0:2048]
      ((float4*)h1l)[tid] = h1v;
    }
    __syncthreads();
    {
      const int d00 = tid >> 4, sp = tid & 15;
      for (int pass = 0; pass < 13; ++pass) {
        const int d = pass * 32 + d00;
        if (d < 400) {
          const int pb = d / 100, pn = d - pb * 100;
          const float* h2r = xinl + pb * 512;
          const float* wpr = A.Wp + pn * 512;
          float a = 0.f;
          for (int jj = 0; jj < 32; ++jj) { const int j = jj * 16 + sp; a += h2r[j] * wpr[j]; }
          a += __shfl_xor(a, 1); a += __shfl_xor(a, 2); a += __shfl_xor(a, 4); a += __shfl_xor(a, 8);
          if (sp == 0) predl[d] = a + A.bp[pn];
        }
      }
    }
    __syncthreads();
    if (uc == 0) {
      for (int i = tid; i < 400; i += 512) {
        const int bl = i / 100, n2 = i - bl * 100;
        A.out[((bq * 4 + bl) * 100 + n2) * HZN + hz] = predl[i];
      }
    }
    for (int k = 0; k < 25; ++k) {
      const int idx = k * 512 + tid;
      const int bl = idx / 3200, rem = idx - bl * 3200;
      const int n2 = rem >> 5, c = rem & 31;
      float s2 = 0.f;
      const int p0 = A.cptr[n2], p1 = A.cptr[n2 + 1];
      for (int p = p0; p < p1; ++p) s2 += A.cnorm[p] * predl[bl * 100 + A.csrc[p]];
      const float pv = predl[bl * 100 + n2];
      const float v = s2 * A.gw[c] + pv * A.gv[c] + A.gb[c];
      xinl[idx] = gelu_f(v) + A.Wemb[n2 * 32 + c];
    }
    __syncthreads();
    // cell1 gates: K = 3200 (xin, bf16 W) + 512 (h1, bf16 W)
    {
      float acc[4][4] = {};
      for (int jj = 0; jj < 25; ++jj) {
        const int j = jj * 128 + sl * 2;
        const unsigned u0w = *(const unsigned*)&A.c1Wih[(size_t)(n) * 3200 + j];
        const unsigned u1w = *(const unsigned*)&A.c1Wih[(size_t)(512 + n) * 3200 + j];
        const unsigned u2w = *(const unsigned*)&A.c1Wih[(size_t)(1024 + n) * 3200 + j];
        const unsigned u3w = *(const unsigned*)&A.c1Wih[(size_t)(1536 + n) * 3200 + j];
        float w0a, w0b, w1a, w1b, w2a, w2b, w3a, w3b;
        bf2(u0w, w0a, w0b); bf2(u1w, w1a, w1b); bf2(u2w, w2a, w2b); bf2(u3w, w3a, w3b);
#pragma unroll
        for (int bl = 0; bl < 4; ++bl) {
          const float2 xv = *(const float2*)&xinl[bl * 3200 + j];
          acc[0][bl] += w0a * xv.x + w0b * xv.y;
          acc[1][bl] += w1a * xv.x + w1b * xv.y;
          acc[2][bl] += w2a * xv.x + w2b * xv.y;
          acc[3][bl] += w3a * xv.x + w3b * xv.y;
        }
      }
      for (int jj = 0; jj < 4; ++jj) {
        const int j = jj * 128 + sl * 2;
        const unsigned u0w = *(const unsigned*)&A.c1Whh[(n) * 512 + j];
        const unsigned u1w = *(const unsigned*)&A.c1Whh[(512 + n) * 512 + j];
        const unsigned u2w = *(const unsigned*)&A.c1Whh[(1024 + n) * 512 + j];
        const unsigned u3w = *(const unsigned*)&A.c1Whh[(1536 + n) * 512 + j];
        float w0a, w0b, w1a, w1b, w2a, w2b, w3a, w3b;
        bf2(u0w, w0a, w0b); bf2(u1w, w1a, w1b); bf2(u2w, w2a, w2b); bf2(u3w, w3a, w3b);
#pragma unroll
        for (int bl = 0; bl < 4; ++bl) {
          const float2 hv = *(const float2*)&h1l[bl * 512 + j];
          acc[0][bl] += w0a * hv.x + w0b * hv.y;
          acc[1][bl] += w1a * hv.x + w1b * hv.y;
          acc[2][bl] += w2a * hv.x + w2b * hv.y;
          acc[3][bl] += w3a * hv.x + w3b * hv.y;
        }
      }
      red64(acc);
      if (sl == 0) {
#pragma unroll
        for (int bl = 0; bl < 4; ++bl) {
          const int b = bq * 4 + bl;
          const float gi = acc[0][bl] + A.c1bih[n] + A.c1bhh[n];
          const float gf = acc[1][bl] + A.c1bih[512 + n] + A.c1bhh[512 + n];
          const float gg = acc[2][bl] + A.c1bih[1024 + n] + A.c1bhh[1024 + n];
          const float go = acc[3][bl] + A.c1bih[1536 + n] + A.c1bhh[1536 + n];
          const float cp = cLd(&A.c1b[b * 512 + n]);
          const float cn = sigm(gf) * cp + sigm(gi) * tanhf(gg);
          const float hn = sigm(go) * tanhf(cn);
          cSt(&A.c1b[b * 512 + n], cn);
          cSt(&A.h1d[nxt * 8192 + b * 512 + n], hn);
        }
      }
    }
    gbar(A.flags, A.gen, bid, tid, bgen);

    // ---- G2 phase: cell2 ----
    {
      float* hAl = lds;
      float* hBl = lds + 2048;
      {
        float4 av = cLd4((const float4*)(A.h1d + nxt * 8192 + bq * 2048) + tid);
        float4 bv = cLd4((const float4*)(A.h2d + cur * 8192 + bq * 2048) + tid);
        vwait();
        ((float4*)hAl)[tid] = av;
        ((float4*)hBl)[tid] = bv;
      }
      __syncthreads();
      float acc[4][4] = {};
      for (int jj = 0; jj < 4; ++jj) {
        const int j = jj * 128 + sl * 2;
        const unsigned a0 = *(const unsigned*)&A.c2Wih[(n) * 512 + j];
        const unsigned a1 = *(const unsigned*)&A.c2Wih[(512 + n) * 512 + j];
        const unsigned a2 = *(const unsigned*)&A.c2Wih[(1024 + n) * 512 + j];
        const unsigned a3 = *(const unsigned*)&A.c2Wih[(1536 + n) * 512 + j];
        const unsigned b0 = *(const unsigned*)&A.c2Whh[(n) * 512 + j];
        const unsigned b1 = *(const unsigned*)&A.c2Whh[(512 + n) * 512 + j];
        const unsigned b2 = *(const unsigned*)&A.c2Whh[(1024 + n) * 512 + j];
        const unsigned b3 = *(const unsigned*)&A.c2Whh[(1536 + n) * 512 + j];
        float wa0a, wa0b, wa1a, wa1b, wa2a, wa2b, wa3a, wa3b;
        float wb0a, wb0b, wb1a, wb1b, wb2a, wb2b, wb3a, wb3b;
        bf2(a0, wa0a, wa0b); bf2(a1, wa1a, wa1b); bf2(a2, wa2a, wa2b); bf2(a3, wa3a, wa3b);
        bf2(b0, wb0a, wb0b); bf2(b1, wb1a, wb1b); bf2(b2, wb2a, wb2b); bf2(b3, wb3a, wb3b);
#pragma unroll
        for (int bl = 0; bl < 4; ++bl) {
          const float2 ha = *(const float2*)&hAl[bl * 512 + j];
          const float2 hb = *(const float2*)&hBl[bl * 512 + j];
          acc[0][bl] += wa0a * ha.x + wa0b * ha.y + wb0a * hb.x + wb0b * hb.y;
          acc[1][bl] += wa1a * ha.x + wa1b * ha.y + wb1a * hb.x + wb1b * hb.y;
          acc[2][bl] += wa2a * ha.x + wa2b * ha.y + wb2a * hb.x + wb2b * hb.y;
          acc[3][bl] += wa3a * ha.x + wa3b * ha.y + wb3a * hb.x + wb3b * hb.y;
        }
      }
      red64(acc);
      if (sl == 0) {
#pragma unroll
        for (int bl = 0; bl < 4; ++bl) {
          const int b = bq * 4 + bl;
          const float gi = acc[0][bl] + A.c2bih[n] + A.c2bhh[n];
          const float gf = acc[1][bl] + A.c2bih[512 + n] + A.c2bhh[512 + n];
          const float gg = acc[2][bl] + A.c2bih[1024 + n] + A.c2bhh[1024 + n];
          const float go = acc[3][bl] + A.c2bih[1536 + n] + A.c2bhh[1536 + n];
          const float cp = cLd(&A.c2b[b * 512 + n]);
          const float cn = sigm(gf) * cp + sigm(gi) * tanhf(gg);
          const float hn = sigm(go) * tanhf(cn);
          cSt(&A.c2b[b * 512 + n], cn);
          cSt(&A.h2d[nxt * 8192 + b * 512 + n], hn);
        }
      }
    }
    gbar(A.flags, A.gen, bid, tid, bgen);
  }
}

// ---------------------------------------------------------------- launch
extern "C" void kernel_launch(void* const* d_in, const int* in_sizes, int n_in,
                              void* d_out, int out_size, void* d_ws, size_t ws_size,
                              hipStream_t stream) {
  (void)in_sizes; (void)n_in; (void)out_size; (void)ws_size;
  const float* window = (const float*)d_in[0];
  const int* ei = (const int*)d_in[1];
  const float* ew = (const float*)d_in[2];
  const float* Wemb = (const float*)d_in[3];
  const float* tgw = (const float*)d_in[4];
  const float* tgv = (const float*)d_in[5];
  const float* tgb = (const float*)d_in[6];
  const float* gw = (const float*)d_in[7];
  const float* gv = (const float*)d_in[8];
  const float* gb = (const float*)d_in[9];
  const float* Wih0 = (const float*)d_in[10];
  const float* Whh0 = (const float*)d_in[11];
  const float* bih0 = (const float*)d_in[12];
  const float* bhh0 = (const float*)d_in[13];
  const float* Wih1 = (const float*)d_in[14];
  const float* Whh1 = (const float*)d_in[15];
  const float* bih1 = (const float*)d_in[16];
  const float* bhh1 = (const float*)d_in[17];
  const float* c1Wih = (const float*)d_in[18];
  const float* c1Whh = (const float*)d_in[19];
  const float* c1bih = (const float*)d_in[20];
  const float* c1bhh = (const float*)d_in[21];
  const float* c2Wih = (const float*)d_in[22];
  const float* c2Whh = (const float*)d_in[23];
  const float* c2bih = (const float*)d_in[24];
  const float* c2bhh = (const float*)d_in[25];
  const float* Wp = (const float*)d_in[26];
  const float* bp = (const float*)d_in[27];

  char* w = (char*)d_ws;
  size_t off = 0;
  auto alloc = [&](size_t bytes) { void* p = w + off; off = (off + bytes + 255) & ~(size_t)255; return p; };
  int* cptr = (int*)alloc(101 * 4);
  int* csrc = (int*)alloc(2000 * 4);
  float* cnorm = (float*)alloc(2000 * 4);
  float* XS = (float*)alloc((size_t)1024 * 3200 * 4);
  float* G0 = (float*)alloc((size_t)1024 * 2048 * 4);
  float* hs0 = (float*)alloc((size_t)64 * 8192 * 4);
  float* hL1 = (float*)alloc((size_t)2 * 8192 * 4);
  float* c0 = (float*)alloc((size_t)8192 * 4);
  float* cL1 = (float*)alloc((size_t)8192 * 4);
  float* h1d = (float*)alloc((size_t)2 * 8192 * 4);
  float* c1b = (float*)alloc((size_t)8192 * 4);
  float* h2d = (float*)alloc((size_t)2 * 8192 * 4);
  float* c2b = (float*)alloc((size_t)8192 * 4);
  unsigned short* c1Wih_bf = (unsigned short*)alloc((size_t)2048 * 3200 * 2);
  unsigned short* c1Whh_bf = (unsigned short*)alloc((size_t)2048 * 512 * 2);
  unsigned short* c2Wih_bf = (unsigned short*)alloc((size_t)2048 * 512 * 2);
  unsigned short* c2Whh_bf = (unsigned short*)alloc((size_t)2048 * 512 * 2);
  unsigned* flags = (unsigned*)alloc(NBLK * 4);
  unsigned* gen = (unsigned*)alloc(64);

  hipMemsetAsync(flags, 0, NBLK * 4, stream);
  hipMemsetAsync(gen, 0, 4, stream);

  setup_kernel<<<1, 256, 0, stream>>>(ei, ew, cptr, csrc, cnorm);
  cvt_bf16<<<(2048 * 3200 + 255) / 256, 256, 0, stream>>>(c1Wih, c1Wih_bf, 2048 * 3200);
  cvt_bf16<<<(2048 * 512 + 255) / 256, 256, 0, stream>>>(c1Whh, c1Whh_bf, 2048 * 512);
  cvt_bf16<<<(2048 * 512 + 255) / 256, 256, 0, stream>>>(c2Wih, c2Wih_bf, 2048 * 512);
  cvt_bf16<<<(2048 * 512 + 255) / 256, 256, 0, stream>>>(c2Whh, c2Whh_bf, 2048 * 512);
  xs_kernel<<<400, 256, 0, stream>>>(window, cptr, csrc, cnorm, tgw, tgv, tgb, Wemb, XS);
  g0_gemm<<<dim3(32, 16), 256, 0, stream>>>(XS, Wih0, bih0, bhh0, G0);

  CoopArgs A;
  A.G0 = G0; A.Whh0 = Whh0;
  A.Wih1 = Wih1; A.Whh1 = Whh1; A.bih1 = bih1; A.bhh1 = bhh1;
  A.c1Wih = c1Wih_bf; A.c1Whh = c1Whh_bf; A.c1bih = c1bih; A.c1bhh = c1bhh;
  A.c2Wih = c2Wih_bf; A.c2Whh = c2Whh_bf; A.c2bih = c2bih; A.c2bhh = c2bhh;
  A.Wp = Wp; A.bp = bp; A.gw = gw; A.gv = gv; A.gb = gb; A.Wemb = Wemb;
  A.cptr = cptr; A.csrc = csrc; A.cnorm = cnorm;
  A.hs0 = hs0; A.hL1 = hL1; A.c0 = c0; A.cL1 = cL1;
  A.h1d = h1d; A.c1b = c1b; A.h2d = h2d; A.c2b = c2b;
  A.flags = flags; A.gen = gen;
  A.out = (float*)d_out;
  void* params[] = { &A };
  hipLaunchCooperativeKernel(coop_kernel, dim3(NBLK), dim3(512), params, 0, stream);
}